// Round 16
// baseline (104.062 us; speedup 1.0000x reference)
//
#include <hip/hip_runtime.h>
#include <hip/hip_bf16.h>
#include <math.h>

// Shapes: B=32, S=32, D=64, E=768
// out layout (floats): [0,32) agg | [32,1056) target_instance | [1056,2080) pred
//                      | [2080,2112) num_seg (as float) | [2112] cos_prior

typedef __bf16 bf16x8 __attribute__((ext_vector_type(8)));
typedef float f32x4 __attribute__((ext_vector_type(4)));

__device__ __forceinline__ unsigned short f2bf(float x) {
    unsigned int u = __float_as_uint(x);
    u = (u + 0x7fffu + ((u >> 16) & 1u)) >> 16;
    return (unsigned short)u;
}
__device__ __forceinline__ float exp2_fast(float x) {
    float r; asm("v_exp_f32 %0, %1" : "=v"(r) : "v"(x)); return r;
}
__device__ __forceinline__ float rcp_fast(float x) {
    float r; asm("v_rcp_f32 %0, %1" : "=v"(r) : "v"(x)); return r;
}
__device__ __forceinline__ unsigned int cvt_pk_bf16(float lo, float hi) {
    unsigned int r; asm("v_cvt_pk_bf16_f32 %0, %1, %2" : "=v"(r) : "v"(lo), "v"(hi)); return r;
}
// tanh-form GELU, log2e folded: x * rcp(1 + 2^(x*(-2.3022081 - 0.10294325 x^2)))
__device__ __forceinline__ float gelu_fast(float x) {
    float t = x * fmaf(x * x, -0.10294325f, -2.3022081f);
    return x * rcp_fast(1.0f + exp2_fast(t));
}
__device__ __forceinline__ float sigmoid_fast(float x) {
    return rcp_fast(1.0f + exp2_fast(x * -1.4426950408889634f));
}
__device__ __forceinline__ float wave_sum(float v) {
    for (int o = 32; o; o >>= 1) v += __shfl_xor(v, o);
    return v;
}
__device__ __forceinline__ float wave_max(float v) {
    for (int o = 32; o; o >>= 1) v = fmaxf(v, __shfl_xor(v, o));
    return v;
}
__device__ __forceinline__ void soft_barrier() {
    __builtin_amdgcn_sched_barrier(0);
    asm volatile("s_waitcnt lgkmcnt(0)" ::: "memory");
    __builtin_amdgcn_s_barrier();
    __builtin_amdgcn_sched_barrier(0);
}
#define GLOAD_LDS16(GP, LP)                                                     \
    __builtin_amdgcn_global_load_lds(                                           \
        (const __attribute__((address_space(1))) unsigned int*)(GP),            \
        (__attribute__((address_space(3))) unsigned int*)(LP), 16, 0, 0)

// ---- prep: W1^T bf16; W2 -> MFMA-fragment layout W2f; normalized bf16 rows ----
__global__ __launch_bounds__(256) void prep_all(const float* __restrict__ W1,
                                                const float* __restrict__ W2,
                                                const float* __restrict__ doc,
                                                const float* __restrict__ sume,
                                                unsigned short* __restrict__ W1t,
                                                unsigned short* __restrict__ W2f,
                                                unsigned short* __restrict__ dnbf,
                                                unsigned short* __restrict__ snbf) {
    __shared__ __align__(16) char shbuf[49152];
    int id = blockIdx.x;
    int t = threadIdx.x;
    if (id < 288) {
        float (*tile)[65] = (float(*)[65])shbuf;
        int bx = id % 12, by = id / 12;
        int r0 = by * 64, c0 = bx * 64;
        #pragma unroll
        for (int p = 0; p < 16; ++p) {
            int r = p * 4 + (t >> 6), c = t & 63;
            tile[r][c] = W1[(r0 + r) * 768 + c0 + c];
        }
        __syncthreads();
        #pragma unroll
        for (int p = 0; p < 16; ++p) {
            int cc = p * 4 + (t >> 6), rr = t & 63;
            W1t[(c0 + cc) * 1536 + r0 + rr] = f2bf(tile[rr][cc]);
        }
    } else if (id < 300) {
        unsigned short* sh = (unsigned short*)shbuf;   // [64][384]
        int kt = id - 288;
        #pragma unroll
        for (int p = 0; p < 96; ++p) {
            int u = p * 256 + t;
            int k = u / 384, n = u - k * 384;
            sh[u] = f2bf(W2[(kt * 64 + k) * 384 + n]);
        }
        __syncthreads();
        #pragma unroll
        for (int p = 0; p < 12; ++p) {
            int u = p * 256 + t;            // 0..3071
            int lane = u & 63;
            int g = u >> 6;                 // 0..47
            int ks = g / 24, fc = g - ks * 24;
            unsigned short tmp[8];
            #pragma unroll
            for (int j = 0; j < 8; ++j)
                tmp[j] = sh[(ks * 32 + (lane >> 4) * 8 + j) * 384 + fc * 16 + (lane & 15)];
            int ktks = kt * 2 + ks;
            *(uint4*)(W2f + ((ktks * 24 + fc) * 64 + lane) * 8) = *(uint4*)tmp;
        }
    } else {
        int row = (id - 300) * 4 + (t >> 6);
        int lane = t & 63;
        const float* p; unsigned short* dst;
        if (row < 2048) { p = doc + row * 768; dst = dnbf + row * 768; }
        else            { p = sume + (row - 2048) * 768; dst = snbf + (row - 2048) * 768; }
        const float* pp = p + lane * 12;
        float4 a0 = *(const float4*)(pp);
        float4 a1 = *(const float4*)(pp + 4);
        float4 a2 = *(const float4*)(pp + 8);
        float s = a0.x*a0.x + a0.y*a0.y + a0.z*a0.z + a0.w*a0.w
                + a1.x*a1.x + a1.y*a1.y + a1.z*a1.z + a1.w*a1.w
                + a2.x*a2.x + a2.y*a2.y + a2.z*a2.z + a2.w*a2.w;
        s = wave_sum(s);
        float r = rsqrtf(fmaxf(s, 1e-12f));
        unsigned short* dd = dst + lane * 12;
        dd[0]  = f2bf(a0.x * r); dd[1]  = f2bf(a0.y * r);
        dd[2]  = f2bf(a0.z * r); dd[3]  = f2bf(a0.w * r);
        dd[4]  = f2bf(a1.x * r); dd[5]  = f2bf(a1.y * r);
        dd[6]  = f2bf(a1.z * r); dd[7]  = f2bf(a1.w * r);
        dd[8]  = f2bf(a2.x * r); dd[9]  = f2bf(a2.y * r);
        dd[10] = f2bf(a2.z * r); dd[11] = f2bf(a2.w * r);
    }
}

// ---- stage-1 GEMM: [doc;sum] @ W1 -> hd (bf16), hs (bf16, +b1 folded) ----
__global__ __launch_bounds__(256) void gemm1(const float* __restrict__ doc,
                                             const float* __restrict__ sume,
                                             const unsigned short* __restrict__ W1t,
                                             const float* __restrict__ b1,
                                             unsigned short* __restrict__ hd,
                                             unsigned short* __restrict__ hs) {
    __shared__ __align__(16) unsigned short Asw[2][128 * 64];
    __shared__ __align__(16) unsigned short Bsw[2][64 * 64];
    int t = threadIdx.x;
    int row0 = blockIdx.y * 128, col0 = blockIdx.x * 64;
    bool is_doc = row0 < 2048;
    const float* A = is_doc ? (doc + row0 * 768) : (sume + (row0 - 2048) * 768);
    int kbase = is_doc ? 0 : 768;
    unsigned short* O = is_doc ? (hd + row0 * 768) : (hs + (row0 - 2048) * 768);

    int l = t & 63, w = t >> 6;
    int wr = w >> 1, wc = w & 1;
    int srow = t >> 3, sko = (t & 7) * 8;
    f32x4 acc[4][2];
    #pragma unroll
    for (int i = 0; i < 4; ++i)
        #pragma unroll
        for (int j = 0; j < 2; ++j) acc[i][j] = (f32x4)0.f;

    float4 fA0[4], fA1[4];
    bf16x8 bB[2];

#define G_LOAD(KT)                                                              \
    {                                                                           \
        _Pragma("unroll")                                                       \
        for (int p = 0; p < 4; ++p) {                                           \
            fA0[p] = *(const float4*)(A + (p * 32 + srow) * 768 + (KT) + sko);  \
            fA1[p] = *(const float4*)(A + (p * 32 + srow) * 768 + (KT) + sko + 4); \
        }                                                                       \
        _Pragma("unroll")                                                       \
        for (int p = 0; p < 2; ++p)                                             \
            bB[p] = *(const bf16x8*)(W1t + (col0 + p * 32 + srow) * 1536 + kbase + (KT) + sko); \
    }

#define G_STORE(BUF)                                                            \
    {                                                                           \
        char* AB = (char*)Asw[BUF];                                             \
        char* BB = (char*)Bsw[BUF];                                             \
        _Pragma("unroll")                                                       \
        for (int p = 0; p < 4; ++p) {                                           \
            uint4 v = make_uint4(cvt_pk_bf16(fA0[p].x, fA0[p].y),               \
                                 cvt_pk_bf16(fA0[p].z, fA0[p].w),               \
                                 cvt_pk_bf16(fA1[p].x, fA1[p].y),               \
                                 cvt_pk_bf16(fA1[p].z, fA1[p].w));              \
            int r = p * 32 + srow;                                              \
            int byte = (r * 128 + sko * 2) ^ ((r & 7) << 4);                    \
            *(uint4*)(AB + byte) = v;                                           \
        }                                                                       \
        _Pragma("unroll")                                                       \
        for (int p = 0; p < 2; ++p) {                                           \
            int r = p * 32 + srow;                                              \
            int byte = (r * 128 + sko * 2) ^ ((r & 7) << 4);                    \
            *(bf16x8*)(BB + byte) = bB[p];                                      \
        }                                                                       \
    }

    G_LOAD(0)
    G_STORE(0)
    G_LOAD(64)
    soft_barrier();

    #pragma unroll 1
    for (int i = 0; i < 12; ++i) {
        int cur = i & 1;
        const char* AR = (const char*)Asw[cur];
        const char* BR = (const char*)Bsw[cur];
        #pragma unroll
        for (int ks = 0; ks < 2; ++ks) {
            int koff = (ks * 32 + (l >> 4) * 8) * 2;
            bf16x8 af[4], bfr[2];
            #pragma unroll
            for (int fr = 0; fr < 4; ++fr) {
                int r = wr * 64 + fr * 16 + (l & 15);
                af[fr] = *(const bf16x8*)(AR + ((r * 128 + koff) ^ ((r & 7) << 4)));
            }
            #pragma unroll
            for (int fc = 0; fc < 2; ++fc) {
                int n = wc * 32 + fc * 16 + (l & 15);
                bfr[fc] = *(const bf16x8*)(BR + ((n * 128 + koff) ^ ((n & 7) << 4)));
            }
            #pragma unroll
            for (int fr = 0; fr < 4; ++fr)
                #pragma unroll
                for (int fc = 0; fc < 2; ++fc)
                    acc[fr][fc] = __builtin_amdgcn_mfma_f32_16x16x32_bf16(af[fr], bfr[fc], acc[fr][fc], 0, 0, 0);
        }
        if (i < 11) {
            G_STORE(cur ^ 1)
            if (i < 10) G_LOAD((i + 2) * 64)
        }
        soft_barrier();
    }
#undef G_LOAD
#undef G_STORE

    #pragma unroll
    for (int fr = 0; fr < 4; ++fr)
        #pragma unroll
        for (int fc = 0; fc < 2; ++fc) {
            int c = col0 + wc * 32 + fc * 16 + (l & 15);
            float badd = is_doc ? 0.0f : b1[c];
            #pragma unroll
            for (int j = 0; j < 4; ++j) {
                int r = wr * 64 + fr * 16 + (l >> 4) * 4 + j;
                O[r * 768 + c] = f2bf(acc[fr][fc][j] + badd);
            }
        }
}

// ---- main fused kernel ----
// blocks [0,32): MFMA cosine per b.
// blocks [32,1056): score, ONE (b,s) per block: 64 rows x 384 cols, 256 thr =
//   4 waves, each wave 64x96 (acc 4x6 f32x4 — same per-wave shape as before).
//   LDS = A 2x4KB + B 3x24KB = exactly 80KB -> TWO blocks/CU: the two resident
//   blocks run desynced, so one block's gelu-VALU phase overlaps the other's
//   MFMA/ds_read phase (m114 wave-level overlap). Counted vmcnt(8) pipeline.
// LDS map: [0,4K) A0 | [4K,8K) A1 | [8K,+24K) B0 | B1 | B2
__global__ __launch_bounds__(256) void score_mfma(
    const unsigned short* __restrict__ hd, const unsigned short* __restrict__ hs,
    const unsigned short* __restrict__ W2f,
    const float* __restrict__ b2, const float* __restrict__ W3,
    const float* __restrict__ b3, const int* __restrict__ ndoc,
    const int* __restrict__ nseg, const unsigned short* __restrict__ dnbf,
    const unsigned short* __restrict__ snbf, float* __restrict__ out,
    float* __restrict__ dscos)
{
    __shared__ __align__(16) char smem[81920];
    float* spart = (float*)smem;          // [4][64] overlay (post-K-loop)
    float* sred  = (float*)smem;          // [4][32] (cosine branch)

    int t = threadIdx.x;
    int l = t & 63, w = t >> 6;

    if (blockIdx.x < 32) {
        // ---- cosine branch: one block per b ----
        int b = (int)blockIdx.x;
        {
            const unsigned short* sb = snbf + b * 32 * 768;
            const unsigned short* db = dnbf + b * 64 * 768;
            int arow = l & 15, ak = (l >> 4) * 8;
            int d0 = w * 16;
            f32x4 acc0 = (f32x4)0.f, acc1 = (f32x4)0.f;
            #pragma unroll
            for (int k = 0; k < 768; k += 32) {
                bf16x8 a0 = *(const bf16x8*)(sb + arow * 768 + k + ak);
                bf16x8 a1 = *(const bf16x8*)(sb + (16 + arow) * 768 + k + ak);
                bf16x8 bb = *(const bf16x8*)(db + (d0 + arow) * 768 + k + ak);
                acc0 = __builtin_amdgcn_mfma_f32_16x16x32_bf16(a0, bb, acc0, 0, 0, 0);
                acc1 = __builtin_amdgcn_mfma_f32_16x16x32_bf16(a1, bb, acc1, 0, 0, 0);
            }
            int nd = ndoc[b];
            int d = d0 + (l & 15);
            float v0[4], v1[4];
            #pragma unroll
            for (int j = 0; j < 4; ++j) {
                v0[j] = (d < nd) ? (1.f - acc0[j]) * 0.5f : 0.f;
                v1[j] = (d < nd) ? (1.f - acc1[j]) * 0.5f : 0.f;
            }
            #pragma unroll
            for (int o = 1; o < 16; o <<= 1) {
                #pragma unroll
                for (int j = 0; j < 4; ++j) {
                    v0[j] = fmaxf(v0[j], __shfl_xor(v0[j], o));
                    v1[j] = fmaxf(v1[j], __shfl_xor(v1[j], o));
                }
            }
            if ((l & 15) == 0) {
                int srw = (l >> 4) * 4;
                #pragma unroll
                for (int j = 0; j < 4; ++j) {
                    sred[w * 32 + srw + j] = v0[j];
                    sred[w * 32 + 16 + srw + j] = v1[j];
                }
            }
        }
        __syncthreads();
        if (t < 32)
            dscos[(int)blockIdx.x * 32 + t] = fmaxf(fmaxf(sred[t], sred[32 + t]),
                                                    fmaxf(sred[64 + t], sred[96 + t]));
        return;
    }

    // ---- score branch: one (b,s) per block ----
    int sb = (int)blockIdx.x - 32;                       // 0..1023
    int lb = (sb & 7) * 128 + (sb >> 3);                 // XCD-contiguous
    int b = lb >> 5, s = lb & 31;
    int nd = ndoc[b], ns = nseg[b];

    f32x4 acc[4][6];
    #pragma unroll
    for (int i = 0; i < 4; ++i)
        #pragma unroll
        for (int j = 0; j < 6; ++j) acc[i][j] = (f32x4)0.f;

    // A staging: thread t -> row d = t>>2 (0..63), k-octet k8 = t&3.
    // Frag-linear A LDS (4 frags x 1KB): frag = d>>4, lane16 = (d&15)|(k8<<4)
    // -> per-wave writes are a lane permutation over one 1KB frag: conflict-free.
    int d = t >> 2;
    int k8 = t & 3;
    const unsigned short* hdp = hd + (b * 64 + d) * 768 + k8 * 8;
    const unsigned short* hsp = hs + (b * 32 + s) * 768 + k8 * 8;
    int abyte = (d >> 4) * 1024 + (((d & 15) | (k8 << 4)) * 16);

    bf16x8 hdA, hsA, hdB, hsB;

#define A_LOAD(KT, HD8, HS8)                                                    \
    {                                                                           \
        HD8 = *(const bf16x8*)(hdp + (KT));                                     \
        HS8 = *(const bf16x8*)(hsp + (KT));                                     \
    }

#define B_STAGE(KC, BUF)                                                        \
    {                                                                           \
        _Pragma("unroll")                                                       \
        for (int q = 0; q < 6; ++q) {                                           \
            int fc = w * 6 + q;                                                 \
            const unsigned short* gsrc = W2f + (((KC) * 24 + fc) * 64 + l) * 8; \
            GLOAD_LDS16(gsrc, smem + 8192 + (BUF) * 24576 + fc * 1024);         \
        }                                                                       \
    }

#define A_STORE(HD8, HS8, BUF)                                                  \
    {                                                                           \
        const unsigned int* hu = (const unsigned int*)&HD8;                     \
        const unsigned int* su = (const unsigned int*)&HS8;                     \
        unsigned int au[4];                                                     \
        _Pragma("unroll")                                                       \
        for (int e = 0; e < 4; ++e) {                                           \
            float x0 = __uint_as_float(hu[e] << 16) + __uint_as_float(su[e] << 16); \
            float x1 = __uint_as_float(hu[e] & 0xffff0000u) + __uint_as_float(su[e] & 0xffff0000u); \
            au[e] = cvt_pk_bf16(gelu_fast(x0), gelu_fast(x1));                  \
        }                                                                       \
        *(uint4*)(smem + (BUF) * 4096 + abyte) = make_uint4(au[0], au[1], au[2], au[3]); \
    }

#define MFMA_PHASE(ABUF, BBUF)                                                  \
    {                                                                           \
        const char* AR = (const char*)smem + (ABUF) * 4096;                     \
        const char* BR = (const char*)smem + 8192 + (BBUF) * 24576;             \
        __builtin_amdgcn_s_setprio(1);                                          \
        bf16x8 af[4];                                                           \
        _Pragma("unroll")                                                       \
        for (int fr = 0; fr < 4; ++fr)                                          \
            af[fr] = *(const bf16x8*)(AR + fr * 1024 + l * 16);                 \
        _Pragma("unroll")                                                       \
        for (int i2 = 0; i2 < 6; ++i2) {                                        \
            bf16x8 bq = *(const bf16x8*)(BR + (w * 6 + i2) * 1024 + l * 16);    \
            _Pragma("unroll")                                                   \
            for (int fr = 0; fr < 4; ++fr)                                      \
                acc[fr][i2] = __builtin_amdgcn_mfma_f32_16x16x32_bf16(af[fr], bq, acc[fr][i2], 0, 0, 0); \
        }                                                                       \
        __builtin_amdgcn_s_setprio(0);                                          \
    }

#define SYNC_CNT(CNTSTR)                                                        \
    __builtin_amdgcn_sched_barrier(0);                                          \
    asm volatile(CNTSTR ::: "memory");                                          \
    __builtin_amdgcn_s_barrier();                                               \
    __builtin_amdgcn_sched_barrier(0);

// one K-step, J literal 0..5 (base % 6 == 0 -> (base+J)%3 = J%3, parity = J&1)
#define K_ITER(J, HDL, HSL, HDS, HSS)                                           \
    {                                                                           \
        B_STAGE(base + (J) + 2, ((J) + 2) % 3)                                  \
        A_LOAD((base + (J) + 2) * 32, HDL, HSL)                                 \
        MFMA_PHASE((J) & 1, (J) % 3)                                            \
        A_STORE(HDS, HSS, ((J) + 1) & 1)                                        \
        SYNC_CNT("s_waitcnt vmcnt(8) lgkmcnt(0)")                               \
    }

    // prologue: B(0)->buf0, B(1)->buf1, A(0)->setA, store A(0), A(1)->setB
    B_STAGE(0, 0)
    B_STAGE(1, 1)
    A_LOAD(0, hdA, hsA)
    A_STORE(hdA, hsA, 0)            // compiler waits A(0); B gloads stay in flight
    A_LOAD(32, hdB, hsB)
    SYNC_CNT("s_waitcnt vmcnt(8) lgkmcnt(0)")   // drains B(0) only

    #pragma unroll 1
    for (int base = 0; base < 18; base += 6) {
        K_ITER(0, hdA, hsA, hdB, hsB)
        K_ITER(1, hdB, hsB, hdA, hsA)
        K_ITER(2, hdA, hsA, hdB, hsB)
        K_ITER(3, hdB, hsB, hdA, hsA)
        K_ITER(4, hdA, hsA, hdB, hsB)
        K_ITER(5, hdB, hsB, hdA, hsA)
    }
    {
        int base = 18;
        K_ITER(0, hdA, hsA, hdB, hsB)        // i=18
        K_ITER(1, hdB, hsB, hdA, hsA)        // i=19
        K_ITER(2, hdA, hsA, hdB, hsB)        // i=20 (stages tile 22)
        K_ITER(3, hdB, hsB, hdA, hsA)        // i=21 (stages tile 23)
    }
    // i=22: no stage; MFMA buf(0, 22%3=1); store tile 23 (regs hdB); drain all
    MFMA_PHASE(0, 1)
    A_STORE(hdB, hsB, 1)
    SYNC_CNT("s_waitcnt vmcnt(0) lgkmcnt(0)")
    // i=23: MFMA buf(1, 23%3=2)
    MFMA_PHASE(1, 2)
#undef A_LOAD
#undef B_STAGE
#undef A_STORE
#undef MFMA_PHASE
#undef SYNC_CNT
#undef K_ITER

    // epilogue: h2 = gelu(acc + b2); partial score over this wave's 96 cols
    float b2v[6], w3v[6];
    #pragma unroll
    for (int i2 = 0; i2 < 6; ++i2) {
        int col = w * 96 + i2 * 16 + (l & 15);
        b2v[i2] = b2[col];
        w3v[i2] = W3[col];
    }
    __syncthreads();    // K-loop LDS reads done before spart overlays A-buffers
    #pragma unroll
    for (int fr = 0; fr < 4; ++fr) {
        #pragma unroll
        for (int j = 0; j < 4; ++j) {
            float pr = 0.f;
            #pragma unroll
            for (int i2 = 0; i2 < 6; ++i2)
                pr += gelu_fast(acc[fr][i2][j] + b2v[i2]) * w3v[i2];
            pr += __shfl_xor(pr, 1);
            pr += __shfl_xor(pr, 2);
            pr += __shfl_xor(pr, 4);
            pr += __shfl_xor(pr, 8);
            if ((l & 15) == 0)
                spart[w * 64 + fr * 16 + (l >> 4) * 4 + j] = pr;
        }
    }
    __syncthreads();
    if (t < 64) {
        int row = t;       // row == d (one s per block)
        float v = spart[row] + spart[64 + row] + spart[128 + row] + spart[192 + row] + b3[0];
        float sc = sigmoid_fast(v);
        float m = (row < nd) ? sc : 0.f;
        m = wave_max(m);
        if (t == 0) {
            float segw = (ns > 10) ? 1.f : 100.f;
            out[1056 + b * 32 + s] = segw * m;
        }
    }
}

// ---- finish: passthrough outputs + cos_prior reduction ----
__global__ __launch_bounds__(1024) void finish_k(const float* __restrict__ agg,
                                                 const float* __restrict__ tinst,
                                                 const int* __restrict__ nseg,
                                                 const float* __restrict__ dscos,
                                                 float* __restrict__ out) {
    __shared__ float red[16];
    int t = threadIdx.x, lane = t & 63, w = t >> 6;
    int b = t >> 5, s = t & 31;
    int ns = nseg[b];
    out[32 + t] = (s < ns) ? tinst[t] : 1.0f;
    if (t < 32) {
        out[t] = agg[t];
        out[2080 + t] = (float)nseg[t];
    }
    float pred = out[1056 + t];
    float v = (s < ns) ? fabsf(dscos[t] - pred) / (float)ns : 0.f;
    v = wave_sum(v);
    if (lane == 0) red[w] = v;
    __syncthreads();
    if (w == 0) {
        float x = (lane < 16) ? red[lane] : 0.f;
        x = wave_sum(x);
        if (lane == 0) out[2112] = x * (1.f / 32.f);
    }
}

extern "C" void kernel_launch(void* const* d_in, const int* in_sizes, int n_in,
                              void* d_out, int out_size, void* d_ws, size_t ws_size,
                              hipStream_t stream) {
    const float* doc   = (const float*)d_in[0];   // [32,64,768]
    const float* sume  = (const float*)d_in[1];   // [32,32,768]
    const int*   ndoc  = (const int*)d_in[2];     // [32]
    const int*   nseg  = (const int*)d_in[3];     // [32]
    const float* agg   = (const float*)d_in[4];   // [32]
    const float* tinst = (const float*)d_in[5];   // [32,32]
    const float* W1    = (const float*)d_in[6];   // [1536,768]
    const float* b1    = (const float*)d_in[7];   // [768]
    const float* W2    = (const float*)d_in[8];   // [768,384]
    const float* b2    = (const float*)d_in[9];   // [384]
    const float* W3    = (const float*)d_in[10];  // [384,1]
    const float* b3    = (const float*)d_in[11];  // [1]
    float* out = (float*)d_out;
    char* ws = (char*)d_ws;

    unsigned short* hd   = (unsigned short*)(ws);             // [2048][768] bf16
    unsigned short* hs   = (unsigned short*)(ws + 3145728);   // [1024][768] bf16 (+b1)
    unsigned short* W1t  = (unsigned short*)(ws + 4718592);   // [768][1536] bf16
    unsigned short* W2f  = (unsigned short*)(ws + 7077888);   // frag-packed W2 bf16
    unsigned short* dnbf = (unsigned short*)(ws + 7667712);   // [2048][768] bf16 normalized
    unsigned short* snbf = (unsigned short*)(ws + 10813440);  // [1024][768] bf16 normalized
    float* dscos = (float*)(ws + 12386304);                   // 1024 f32

    prep_all<<<1068, 256, 0, stream>>>(W1, W2, doc, sume, W1t, W2f, dnbf, snbf);
    gemm1<<<dim3(12, 24), 256, 0, stream>>>(doc, sume, W1t, b1, hd, hs);
    score_mfma<<<1056, 256, 0, stream>>>(hd, hs, W2f, b2, W3, b3, ndoc, nseg,
                                         dnbf, snbf, out, dscos);
    finish_k<<<1, 1024, 0, stream>>>(agg, tinst, nseg, dscos, out);
}

// Round 17
// 99.245 us; speedup vs baseline: 1.0485x; 1.0485x over previous
//
#include <hip/hip_runtime.h>
#include <hip/hip_bf16.h>
#include <math.h>

// Shapes: B=32, S=32, D=64, E=768
// out layout (floats): [0,32) agg | [32,1056) target_instance | [1056,2080) pred
//                      | [2080,2112) num_seg (as float) | [2112] cos_prior

typedef __bf16 bf16x8 __attribute__((ext_vector_type(8)));
typedef float f32x4 __attribute__((ext_vector_type(4)));

__device__ __forceinline__ unsigned short f2bf(float x) {
    unsigned int u = __float_as_uint(x);
    u = (u + 0x7fffu + ((u >> 16) & 1u)) >> 16;
    return (unsigned short)u;
}
// guaranteed-native transcendentals (1 inst each; v_exp_f32 computes 2^x)
__device__ __forceinline__ float exp2_fast(float x) {
    float r; asm("v_exp_f32 %0, %1" : "=v"(r) : "v"(x)); return r;
}
__device__ __forceinline__ float rcp_fast(float x) {
    float r; asm("v_rcp_f32 %0, %1" : "=v"(r) : "v"(x)); return r;
}
// packed f32x2 -> bf16x2 (1 inst)
__device__ __forceinline__ unsigned int cvt_pk_bf16(float lo, float hi) {
    unsigned int r; asm("v_cvt_pk_bf16_f32 %0, %1, %2" : "=v"(r) : "v"(lo), "v"(hi)); return r;
}
// tanh-form GELU with log2e folded: x * rcp(1 + 2^(x*(-2.3022081 - 0.10294325 x^2)))
__device__ __forceinline__ float gelu_fast(float x) {
    float t = x * fmaf(x * x, -0.10294325f, -2.3022081f);
    return x * rcp_fast(1.0f + exp2_fast(t));
}
__device__ __forceinline__ float sigmoid_fast(float x) {
    return rcp_fast(1.0f + exp2_fast(x * -1.4426950408889634f));
}
__device__ __forceinline__ float wave_sum(float v) {
    for (int o = 32; o; o >>= 1) v += __shfl_xor(v, o);
    return v;
}
__device__ __forceinline__ float wave_max(float v) {
    for (int o = 32; o; o >>= 1) v = fmaxf(v, __shfl_xor(v, o));
    return v;
}
__device__ __forceinline__ void soft_barrier() {
    __builtin_amdgcn_sched_barrier(0);
    asm volatile("s_waitcnt lgkmcnt(0)" ::: "memory");
    __builtin_amdgcn_s_barrier();
    __builtin_amdgcn_sched_barrier(0);
}
// async global -> LDS, 16B per lane; LDS dest = uniform base + lane*16
#define GLOAD_LDS16(GP, LP)                                                     \
    __builtin_amdgcn_global_load_lds(                                           \
        (const __attribute__((address_space(1))) unsigned int*)(GP),            \
        (__attribute__((address_space(3))) unsigned int*)(LP), 16, 0, 0)

// ---- prep: W1^T bf16; W2 -> MFMA-fragment layout W2f; normalized bf16 rows ----
__global__ __launch_bounds__(256) void prep_all(const float* __restrict__ W1,
                                                const float* __restrict__ W2,
                                                const float* __restrict__ doc,
                                                const float* __restrict__ sume,
                                                unsigned short* __restrict__ W1t,
                                                unsigned short* __restrict__ W2f,
                                                unsigned short* __restrict__ dnbf,
                                                unsigned short* __restrict__ snbf) {
    __shared__ __align__(16) char shbuf[49152];
    int id = blockIdx.x;
    int t = threadIdx.x;
    if (id < 288) {
        float (*tile)[65] = (float(*)[65])shbuf;
        int bx = id % 12, by = id / 12;
        int r0 = by * 64, c0 = bx * 64;
        #pragma unroll
        for (int p = 0; p < 16; ++p) {
            int r = p * 4 + (t >> 6), c = t & 63;
            tile[r][c] = W1[(r0 + r) * 768 + c0 + c];
        }
        __syncthreads();
        // vectorized transpose writes: each thread emits ushort2 (rows rr, rr+1)
        #pragma unroll
        for (int p = 0; p < 8; ++p) {
            int cc = p * 8 + (t >> 5);
            int rr = (t & 31) * 2;
            unsigned short lo = f2bf(tile[rr][cc]);
            unsigned short hi = f2bf(tile[rr + 1][cc]);
            unsigned int pk = (unsigned int)lo | ((unsigned int)hi << 16);
            *(unsigned int*)(W1t + (c0 + cc) * 1536 + r0 + rr) = pk;
        }
    } else if (id < 300) {
        unsigned short* sh = (unsigned short*)shbuf;   // [64][384]
        int kt = id - 288;
        #pragma unroll
        for (int p = 0; p < 96; ++p) {
            int u = p * 256 + t;
            int k = u / 384, n = u - k * 384;
            sh[u] = f2bf(W2[(kt * 64 + k) * 384 + n]);
        }
        __syncthreads();
        #pragma unroll
        for (int p = 0; p < 12; ++p) {
            int u = p * 256 + t;            // 0..3071
            int lane = u & 63;
            int g = u >> 6;                 // 0..47
            int ks = g / 24, fc = g - ks * 24;
            unsigned short tmp[8];
            #pragma unroll
            for (int j = 0; j < 8; ++j)
                tmp[j] = sh[(ks * 32 + (lane >> 4) * 8 + j) * 384 + fc * 16 + (lane & 15)];
            int ktks = kt * 2 + ks;
            *(uint4*)(W2f + ((ktks * 24 + fc) * 64 + lane) * 8) = *(uint4*)tmp;
        }
    } else {
        int row = (id - 300) * 4 + (t >> 6);
        int lane = t & 63;
        const float* p; unsigned short* dst;
        if (row < 2048) { p = doc + row * 768; dst = dnbf + row * 768; }
        else            { p = sume + (row - 2048) * 768; dst = snbf + (row - 2048) * 768; }
        const float* pp = p + lane * 12;
        float4 a0 = *(const float4*)(pp);
        float4 a1 = *(const float4*)(pp + 4);
        float4 a2 = *(const float4*)(pp + 8);
        float s = a0.x*a0.x + a0.y*a0.y + a0.z*a0.z + a0.w*a0.w
                + a1.x*a1.x + a1.y*a1.y + a1.z*a1.z + a1.w*a1.w
                + a2.x*a2.x + a2.y*a2.y + a2.z*a2.z + a2.w*a2.w;
        s = wave_sum(s);
        float r = rsqrtf(fmaxf(s, 1e-12f));
        unsigned short* dd = dst + lane * 12;
        dd[0]  = f2bf(a0.x * r); dd[1]  = f2bf(a0.y * r);
        dd[2]  = f2bf(a0.z * r); dd[3]  = f2bf(a0.w * r);
        dd[4]  = f2bf(a1.x * r); dd[5]  = f2bf(a1.y * r);
        dd[6]  = f2bf(a1.z * r); dd[7]  = f2bf(a1.w * r);
        dd[8]  = f2bf(a2.x * r); dd[9]  = f2bf(a2.y * r);
        dd[10] = f2bf(a2.z * r); dd[11] = f2bf(a2.w * r);
    }
}

// ---- stage-1 GEMM: [doc;sum] @ W1 -> hd (bf16), hs (bf16, +b1 folded) ----
__global__ __launch_bounds__(256) void gemm1(const float* __restrict__ doc,
                                             const float* __restrict__ sume,
                                             const unsigned short* __restrict__ W1t,
                                             const float* __restrict__ b1,
                                             unsigned short* __restrict__ hd,
                                             unsigned short* __restrict__ hs) {
    __shared__ __align__(16) unsigned short Asw[2][128 * 64];
    __shared__ __align__(16) unsigned short Bsw[2][64 * 64];
    int t = threadIdx.x;
    int row0 = blockIdx.y * 128, col0 = blockIdx.x * 64;
    bool is_doc = row0 < 2048;
    const float* A = is_doc ? (doc + row0 * 768) : (sume + (row0 - 2048) * 768);
    int kbase = is_doc ? 0 : 768;
    unsigned short* O = is_doc ? (hd + row0 * 768) : (hs + (row0 - 2048) * 768);

    int l = t & 63, w = t >> 6;
    int wr = w >> 1, wc = w & 1;
    int srow = t >> 3, sko = (t & 7) * 8;
    f32x4 acc[4][2];
    #pragma unroll
    for (int i = 0; i < 4; ++i)
        #pragma unroll
        for (int j = 0; j < 2; ++j) acc[i][j] = (f32x4)0.f;

    float4 fA0[4], fA1[4];
    bf16x8 bB[2];

#define G_LOAD(KT)                                                              \
    {                                                                           \
        _Pragma("unroll")                                                       \
        for (int p = 0; p < 4; ++p) {                                           \
            fA0[p] = *(const float4*)(A + (p * 32 + srow) * 768 + (KT) + sko);  \
            fA1[p] = *(const float4*)(A + (p * 32 + srow) * 768 + (KT) + sko + 4); \
        }                                                                       \
        _Pragma("unroll")                                                       \
        for (int p = 0; p < 2; ++p)                                             \
            bB[p] = *(const bf16x8*)(W1t + (col0 + p * 32 + srow) * 1536 + kbase + (KT) + sko); \
    }

#define G_STORE(BUF)                                                            \
    {                                                                           \
        char* AB = (char*)Asw[BUF];                                             \
        char* BB = (char*)Bsw[BUF];                                             \
        _Pragma("unroll")                                                       \
        for (int p = 0; p < 4; ++p) {                                           \
            uint4 v = make_uint4(cvt_pk_bf16(fA0[p].x, fA0[p].y),               \
                                 cvt_pk_bf16(fA0[p].z, fA0[p].w),               \
                                 cvt_pk_bf16(fA1[p].x, fA1[p].y),               \
                                 cvt_pk_bf16(fA1[p].z, fA1[p].w));              \
            int r = p * 32 + srow;                                              \
            int byte = (r * 128 + sko * 2) ^ ((r & 7) << 4);                    \
            *(uint4*)(AB + byte) = v;                                           \
        }                                                                       \
        _Pragma("unroll")                                                       \
        for (int p = 0; p < 2; ++p) {                                           \
            int r = p * 32 + srow;                                              \
            int byte = (r * 128 + sko * 2) ^ ((r & 7) << 4);                    \
            *(bf16x8*)(BB + byte) = bB[p];                                      \
        }                                                                       \
    }

    G_LOAD(0)
    G_STORE(0)
    G_LOAD(64)
    soft_barrier();

    #pragma unroll 1
    for (int i = 0; i < 12; ++i) {
        int cur = i & 1;
        const char* AR = (const char*)Asw[cur];
        const char* BR = (const char*)Bsw[cur];
        #pragma unroll
        for (int ks = 0; ks < 2; ++ks) {
            int koff = (ks * 32 + (l >> 4) * 8) * 2;
            bf16x8 af[4], bfr[2];
            #pragma unroll
            for (int fr = 0; fr < 4; ++fr) {
                int r = wr * 64 + fr * 16 + (l & 15);
                af[fr] = *(const bf16x8*)(AR + ((r * 128 + koff) ^ ((r & 7) << 4)));
            }
            #pragma unroll
            for (int fc = 0; fc < 2; ++fc) {
                int n = wc * 32 + fc * 16 + (l & 15);
                bfr[fc] = *(const bf16x8*)(BR + ((n * 128 + koff) ^ ((n & 7) << 4)));
            }
            #pragma unroll
            for (int fr = 0; fr < 4; ++fr)
                #pragma unroll
                for (int fc = 0; fc < 2; ++fc)
                    acc[fr][fc] = __builtin_amdgcn_mfma_f32_16x16x32_bf16(af[fr], bfr[fc], acc[fr][fc], 0, 0, 0);
        }
        if (i < 11) {
            G_STORE(cur ^ 1)
            if (i < 10) G_LOAD((i + 2) * 64)
        }
        soft_barrier();
    }
#undef G_LOAD
#undef G_STORE

    #pragma unroll
    for (int fr = 0; fr < 4; ++fr)
        #pragma unroll
        for (int fc = 0; fc < 2; ++fc) {
            int c = col0 + wc * 32 + fc * 16 + (l & 15);
            float badd = is_doc ? 0.0f : b1[c];
            #pragma unroll
            for (int j = 0; j < 4; ++j) {
                int r = wr * 64 + fr * 16 + (l >> 4) * 4 + j;
                O[r * 768 + c] = f2bf(acc[fr][fc][j] + badd);
            }
        }
}

// ---- main fused kernel (R14 configuration — measured best) ----
// blocks [0,32): MFMA cosine per b.
// blocks [32,544): score GEMM tile = 128 rows (2 s x 64 d) x 384 cols, 512 thr,
//   8 waves (2 row-grp x 4 col-grp => wave 64x96, acc 4x6 f32x4).
//   BK=32, 24 steps. DEEP PIPELINE: B triple-buffered (stage i+2 while reading i),
//   A regs double-set + LDS dbuf. Pre-barrier wait = vmcnt(5) — NEVER 0.
// LDS map: [0,8K) A0 | [8K,16K) A1 | [16K,+24K) B0 | B1 | B2  (88 KB total)
__global__ __launch_bounds__(512) void score_mfma(
    const unsigned short* __restrict__ hd, const unsigned short* __restrict__ hs,
    const unsigned short* __restrict__ W2f,
    const float* __restrict__ b2, const float* __restrict__ W3,
    const float* __restrict__ b3, const int* __restrict__ ndoc,
    const int* __restrict__ nseg, const unsigned short* __restrict__ dnbf,
    const unsigned short* __restrict__ snbf, float* __restrict__ out,
    float* __restrict__ dscos)
{
    __shared__ __align__(16) char smem[90112];
    float* spart = (float*)smem;          // [4][128] overlay (post-K-loop)
    float* sred  = (float*)smem;          // [4][32] (cosine branch)

    int t = threadIdx.x;
    int l = t & 63, w = t >> 6;

    if (blockIdx.x < 32) {
        // ---- cosine branch: one block per b ----
        int b = (int)blockIdx.x;
        if (w < 4) {
            const unsigned short* sb = snbf + b * 32 * 768;
            const unsigned short* db = dnbf + b * 64 * 768;
            int arow = l & 15, ak = (l >> 4) * 8;
            int d0 = w * 16;
            f32x4 acc0 = (f32x4)0.f, acc1 = (f32x4)0.f;
            #pragma unroll
            for (int k = 0; k < 768; k += 32) {
                bf16x8 a0 = *(const bf16x8*)(sb + arow * 768 + k + ak);
                bf16x8 a1 = *(const bf16x8*)(sb + (16 + arow) * 768 + k + ak);
                bf16x8 bb = *(const bf16x8*)(db + (d0 + arow) * 768 + k + ak);
                acc0 = __builtin_amdgcn_mfma_f32_16x16x32_bf16(a0, bb, acc0, 0, 0, 0);
                acc1 = __builtin_amdgcn_mfma_f32_16x16x32_bf16(a1, bb, acc1, 0, 0, 0);
            }
            int nd = ndoc[b];
            int d = d0 + (l & 15);
            float v0[4], v1[4];
            #pragma unroll
            for (int j = 0; j < 4; ++j) {
                v0[j] = (d < nd) ? (1.f - acc0[j]) * 0.5f : 0.f;
                v1[j] = (d < nd) ? (1.f - acc1[j]) * 0.5f : 0.f;
            }
            #pragma unroll
            for (int o = 1; o < 16; o <<= 1) {
                #pragma unroll
                for (int j = 0; j < 4; ++j) {
                    v0[j] = fmaxf(v0[j], __shfl_xor(v0[j], o));
                    v1[j] = fmaxf(v1[j], __shfl_xor(v1[j], o));
                }
            }
            if ((l & 15) == 0) {
                int srw = (l >> 4) * 4;
                #pragma unroll
                for (int j = 0; j < 4; ++j) {
                    sred[w * 32 + srw + j] = v0[j];
                    sred[w * 32 + 16 + srw + j] = v1[j];
                }
            }
        }
        __syncthreads();
        if (t < 32)
            dscos[(int)blockIdx.x * 32 + t] = fmaxf(fmaxf(sred[t], sred[32 + t]),
                                                    fmaxf(sred[64 + t], sred[96 + t]));
        return;
    }

    // ---- score branch ----
    int sb = (int)blockIdx.x - 32;                       // 0..511
    int lb = (sb & 7) * 64 + (sb >> 3);                  // XCD-contiguous
    int b = lb >> 4, sp = lb & 15;
    int s0 = sp * 2;
    int nd = ndoc[b], ns = nseg[b];
    int wr = w >> 2, wc = w & 3;            // 2 row-groups x 4 col-groups

    f32x4 acc[4][6];
    #pragma unroll
    for (int i = 0; i < 4; ++i)
        #pragma unroll
        for (int j = 0; j < 6; ++j) acc[i][j] = (f32x4)0.f;

    // A staging: thread t stages row r = t>>2 (0..127), k-octet k8 = t&3 (8 bf16)
    int r = t >> 2;
    int k8 = t & 3;
    int d = r & 63, sl = r >> 6;
    const unsigned short* hdp = hd + (b * 64 + d) * 768 + k8 * 8;
    const unsigned short* hsp = hs + (b * 32 + s0 + sl) * 768 + k8 * 8;
    int abyte = ((r >> 4) * 1024 + k8 * 256 + (r & 15) * 16) ^ (k8 << 4);  // bank-spread writes

    bf16x8 hdA, hsA, hdB, hsB;

#define A_LOAD(KT, HD8, HS8)                                                    \
    {                                                                           \
        HD8 = *(const bf16x8*)(hdp + (KT));                                     \
        HS8 = *(const bf16x8*)(hsp + (KT));                                     \
    }

#define B_STAGE(KC, BUF)                                                        \
    {                                                                           \
        _Pragma("unroll")                                                       \
        for (int q = 0; q < 3; ++q) {                                           \
            int fc = w * 3 + q;                                                 \
            const unsigned short* gsrc = W2f + (((KC) * 24 + fc) * 64 + l) * 8; \
            GLOAD_LDS16(gsrc, smem + 16384 + (BUF) * 24576 + fc * 1024);        \
        }                                                                       \
    }

#define A_STORE(HD8, HS8, BUF)                                                  \
    {                                                                           \
        const unsigned int* hu = (const unsigned int*)&HD8;                     \
        const unsigned int* su = (const unsigned int*)&HS8;                     \
        unsigned int au[4];                                                     \
        _Pragma("unroll")                                                       \
        for (int e = 0; e < 4; ++e) {                                           \
            float x0 = __uint_as_float(hu[e] << 16) + __uint_as_float(su[e] << 16); \
            float x1 = __uint_as_float(hu[e] & 0xffff0000u) + __uint_as_float(su[e] & 0xffff0000u); \
            au[e] = cvt_pk_bf16(gelu_fast(x0), gelu_fast(x1));                  \
        }                                                                       \
        *(uint4*)(smem + (BUF) * 8192 + abyte) = make_uint4(au[0], au[1], au[2], au[3]); \
    }

#define MFMA_PHASE(ABUF, BBUF)                                                  \
    {                                                                           \
        const char* AR = (const char*)smem + (ABUF) * 8192;                     \
        const char* BR = (const char*)smem + 16384 + (BBUF) * 24576;            \
        __builtin_amdgcn_s_setprio(1);                                          \
        bf16x8 af[4];                                                           \
        _Pragma("unroll")                                                       \
        for (int fr = 0; fr < 4; ++fr)                                          \
            af[fr] = *(const bf16x8*)(AR + (wr * 4 + fr) * 1024                 \
                                         + ((l * 16) ^ ((l >> 4) << 4)));       \
        _Pragma("unroll")                                                       \
        for (int i2 = 0; i2 < 6; ++i2) {                                        \
            bf16x8 bq = *(const bf16x8*)(BR + (wc * 6 + i2) * 1024 + l * 16);   \
            _Pragma("unroll")                                                   \
            for (int fr = 0; fr < 4; ++fr)                                      \
                acc[fr][i2] = __builtin_amdgcn_mfma_f32_16x16x32_bf16(af[fr], bq, acc[fr][i2], 0, 0, 0); \
        }                                                                       \
        __builtin_amdgcn_s_setprio(0);                                          \
    }

#define SYNC_CNT()                                                              \
    __builtin_amdgcn_sched_barrier(0);                                          \
    asm volatile("s_waitcnt vmcnt(5) lgkmcnt(0)" ::: "memory");                 \
    __builtin_amdgcn_s_barrier();                                               \
    __builtin_amdgcn_sched_barrier(0);

// one K-step; J = literal 0..5 (base multiple of 6 -> (base+J)%3 = J%3, parity = J&1)
#define K_ITER(J, HDL, HSL, HDS, HSS)                                           \
    {                                                                           \
        int i_ = base + (J);                                                    \
        if (i_ < 22) {                                                          \
            B_STAGE(i_ + 2, ((J) + 2) % 3)                                      \
            A_LOAD((i_ + 2) * 32, HDL, HSL)                                     \
        }                                                                       \
        MFMA_PHASE((J) & 1, (J) % 3)                                            \
        if (i_ < 23) A_STORE(HDS, HSS, ((J) + 1) & 1)                           \
        SYNC_CNT()                                                              \
    }

    // prologue: A(0)->set A; B(0)->buf0; B(1)->buf1; store A(0); A(1)->set B
    A_LOAD(0, hdA, hsA)
    B_STAGE(0, 0)
    B_STAGE(1, 1)
    A_STORE(hdA, hsA, 0)            // implicit wait on A(0); B0/B1 stay in flight
    A_LOAD(32, hdB, hsB)
    SYNC_CNT()                      // vmcnt(5): drains B0 only

    #pragma unroll 1
    for (int base = 0; base < 24; base += 6) {
        K_ITER(0, hdA, hsA, hdB, hsB)
        K_ITER(1, hdB, hsB, hdA, hsA)
        K_ITER(2, hdA, hsA, hdB, hsB)
        K_ITER(3, hdB, hsB, hdA, hsA)
        K_ITER(4, hdA, hsA, hdB, hsB)
        K_ITER(5, hdB, hsB, hdA, hsA)
    }
#undef A_LOAD
#undef B_STAGE
#undef A_STORE
#undef MFMA_PHASE
#undef SYNC_CNT
#undef K_ITER

    // epilogue: h2 = gelu(acc + b2); partial score over this wave's 96 cols
    float b2v[6], w3v[6];
    #pragma unroll
    for (int i2 = 0; i2 < 6; ++i2) {
        int col = wc * 96 + i2 * 16 + (l & 15);
        b2v[i2] = b2[col];
        w3v[i2] = W3[col];
    }
    __syncthreads();    // K-loop LDS reads done before spart overlays A-buffers
    #pragma unroll
    for (int fr = 0; fr < 4; ++fr) {
        #pragma unroll
        for (int j = 0; j < 4; ++j) {
            float pr = 0.f;
            #pragma unroll
            for (int i2 = 0; i2 < 6; ++i2)
                pr += gelu_fast(acc[fr][i2][j] + b2v[i2]) * w3v[i2];
            pr += __shfl_xor(pr, 1);
            pr += __shfl_xor(pr, 2);
            pr += __shfl_xor(pr, 4);
            pr += __shfl_xor(pr, 8);
            if ((l & 15) == 0)
                spart[wc * 128 + wr * 64 + fr * 16 + (l >> 4) * 4 + j] = pr;
        }
    }
    __syncthreads();
    if (t < 128) {
        int row = t;
        float v = spart[row] + spart[128 + row] + spart[256 + row] + spart[384 + row] + b3[0];
        float sc = sigmoid_fast(v);
        int dd = row & 63, sl2 = row >> 6;
        float m = (dd < nd) ? sc : 0.f;
        m = wave_max(m);
        if ((t & 63) == 0) {
            float segw = (ns > 10) ? 1.f : 100.f;
            out[1056 + b * 32 + s0 + sl2] = segw * m;
        }
    }
}

// ---- finish: passthrough outputs + cos_prior reduction ----
__global__ __launch_bounds__(1024) void finish_k(const float* __restrict__ agg,
                                                 const float* __restrict__ tinst,
                                                 const int* __restrict__ nseg,
                                                 const float* __restrict__ dscos,
                                                 float* __restrict__ out) {
    __shared__ float red[16];
    int t = threadIdx.x, lane = t & 63, w = t >> 6;
    int b = t >> 5, s = t & 31;
    int ns = nseg[b];
    out[32 + t] = (s < ns) ? tinst[t] : 1.0f;
    if (t < 32) {
        out[t] = agg[t];
        out[2080 + t] = (float)nseg[t];
    }
    float pred = out[1056 + t];
    float v = (s < ns) ? fabsf(dscos[t] - pred) / (float)ns : 0.f;
    v = wave_sum(v);
    if (lane == 0) red[w] = v;
    __syncthreads();
    if (w == 0) {
        float x = (lane < 16) ? red[lane] : 0.f;
        x = wave_sum(x);
        if (lane == 0) out[2112] = x * (1.f / 32.f);
    }
}

extern "C" void kernel_launch(void* const* d_in, const int* in_sizes, int n_in,
                              void* d_out, int out_size, void* d_ws, size_t ws_size,
                              hipStream_t stream) {
    const float* doc   = (const float*)d_in[0];   // [32,64,768]
    const float* sume  = (const float*)d_in[1];   // [32,32,768]
    const int*   ndoc  = (const int*)d_in[2];     // [32]
    const int*   nseg  = (const int*)d_in[3];     // [32]
    const float* agg   = (const float*)d_in[4];   // [32]
    const float* tinst = (const float*)d_in[5];   // [32,32]
    const float* W1    = (const float*)d_in[6];   // [1536,768]
    const float* b1    = (const float*)d_in[7];   // [768]
    const float* W2    = (const float*)d_in[8];   // [768,384]
    const float* b2    = (const float*)d_in[9];   // [384]
    const float* W3    = (const float*)d_in[10];  // [384,1]
    const float* b3    = (const float*)d_in[11];  // [1]
    float* out = (float*)d_out;
    char* ws = (char*)d_ws;

    unsigned short* hd   = (unsigned short*)(ws);             // [2048][768] bf16
    unsigned short* hs   = (unsigned short*)(ws + 3145728);   // [1024][768] bf16 (+b1)
    unsigned short* W1t  = (unsigned short*)(ws + 4718592);   // [768][1536] bf16
    unsigned short* W2f  = (unsigned short*)(ws + 7077888);   // frag-packed W2 bf16
    unsigned short* dnbf = (unsigned short*)(ws + 7667712);   // [2048][768] bf16 normalized
    unsigned short* snbf = (unsigned short*)(ws + 10813440);  // [1024][768] bf16 normalized
    float* dscos = (float*)(ws + 12386304);                   // 1024 f32

    prep_all<<<1068, 256, 0, stream>>>(W1, W2, doc, sume, W1t, W2f, dnbf, snbf);
    gemm1<<<dim3(12, 24), 256, 0, stream>>>(doc, sume, W1t, b1, hd, hs);
    score_mfma<<<544, 512, 0, stream>>>(hd, hs, W2f, b2, W3, b3, ndoc, nseg,
                                        dnbf, snbf, out, dscos);
    finish_k<<<1, 1024, 0, stream>>>(agg, tinst, nseg, dscos, out);
}

// Round 19
// 97.978 us; speedup vs baseline: 1.0621x; 1.0129x over previous
//
#include <hip/hip_runtime.h>
#include <hip/hip_bf16.h>
#include <math.h>

// Shapes: B=32, S=32, D=64, E=768
// out layout (floats): [0,32) agg | [32,1056) target_instance | [1056,2080) pred
//                      | [2080,2112) num_seg (as float) | [2112] cos_prior

typedef __bf16 bf16x8 __attribute__((ext_vector_type(8)));
typedef float f32x4 __attribute__((ext_vector_type(4)));

__device__ __forceinline__ unsigned short f2bf(float x) {
    unsigned int u = __float_as_uint(x);
    u = (u + 0x7fffu + ((u >> 16) & 1u)) >> 16;
    return (unsigned short)u;
}
// guaranteed-native transcendentals (1 inst each; v_exp_f32 computes 2^x)
__device__ __forceinline__ float exp2_fast(float x) {
    float r; asm("v_exp_f32 %0, %1" : "=v"(r) : "v"(x)); return r;
}
__device__ __forceinline__ float rcp_fast(float x) {
    float r; asm("v_rcp_f32 %0, %1" : "=v"(r) : "v"(x)); return r;
}
// packed f32x2 -> bf16x2 (1 inst)
__device__ __forceinline__ unsigned int cvt_pk_bf16(float lo, float hi) {
    unsigned int r; asm("v_cvt_pk_bf16_f32 %0, %1, %2" : "=v"(r) : "v"(lo), "v"(hi)); return r;
}
// tanh-form GELU with log2e folded: x * rcp(1 + 2^(x*(-2.3022081 - 0.10294325 x^2)))
__device__ __forceinline__ float gelu_fast(float x) {
    float t = x * fmaf(x * x, -0.10294325f, -2.3022081f);
    return x * rcp_fast(1.0f + exp2_fast(t));
}
__device__ __forceinline__ float sigmoid_fast(float x) {
    return rcp_fast(1.0f + exp2_fast(x * -1.4426950408889634f));
}
__device__ __forceinline__ float wave_sum(float v) {
    for (int o = 32; o; o >>= 1) v += __shfl_xor(v, o);
    return v;
}
__device__ __forceinline__ float wave_max(float v) {
    for (int o = 32; o; o >>= 1) v = fmaxf(v, __shfl_xor(v, o));
    return v;
}
__device__ __forceinline__ void soft_barrier() {
    __builtin_amdgcn_sched_barrier(0);
    asm volatile("s_waitcnt lgkmcnt(0)" ::: "memory");
    __builtin_amdgcn_s_barrier();
    __builtin_amdgcn_sched_barrier(0);
}
// async global -> LDS, 16B per lane; LDS dest = uniform base + lane*16
#define GLOAD_LDS16(GP, LP)                                                     \
    __builtin_amdgcn_global_load_lds(                                           \
        (const __attribute__((address_space(1))) unsigned int*)(GP),            \
        (__attribute__((address_space(3))) unsigned int*)(LP), 16, 0, 0)

// ---- launch 1: W1^T bf16 only (gemm1's sole dependency) ----
__global__ __launch_bounds__(256) void prep_w1t(const float* __restrict__ W1,
                                                unsigned short* __restrict__ W1t) {
    __shared__ float tile[64][65];
    int id = blockIdx.x;
    int t = threadIdx.x;
    int bx = id % 12, by = id / 12;
    int r0 = by * 64, c0 = bx * 64;
    #pragma unroll
    for (int p = 0; p < 16; ++p) {
        int r = p * 4 + (t >> 6), c = t & 63;
        tile[r][c] = W1[(r0 + r) * 768 + c0 + c];
    }
    __syncthreads();
    #pragma unroll
    for (int p = 0; p < 8; ++p) {
        int cc = p * 8 + (t >> 5);
        int rr = (t & 31) * 2;
        unsigned short lo = f2bf(tile[rr][cc]);
        unsigned short hi = f2bf(tile[rr + 1][cc]);
        unsigned int pk = (unsigned int)lo | ((unsigned int)hi << 16);
        *(unsigned int*)(W1t + (c0 + cc) * 1536 + r0 + rr) = pk;
    }
}

// ---- launch 2 (combined): blocks [0,288) = gemm1 (EXACT R17 body);
//      [288,300) = W2f pack; [300,1068) = normalize rows. The light prep
//      blocks co-schedule with gemm1 and hide under it.
__global__ __launch_bounds__(256) void mid_all(const float* __restrict__ doc,
                                               const float* __restrict__ sume,
                                               const unsigned short* __restrict__ W1t,
                                               const float* __restrict__ b1,
                                               const float* __restrict__ W2,
                                               unsigned short* __restrict__ hd,
                                               unsigned short* __restrict__ hs,
                                               unsigned short* __restrict__ W2f,
                                               unsigned short* __restrict__ dnbf,
                                               unsigned short* __restrict__ snbf) {
    __shared__ __align__(16) char shbuf[49152];
    int id = blockIdx.x;
    int t = threadIdx.x;

    if (id < 288) {
        // ---- gemm1: EXACT R17 body; 128x64 tile ----
        unsigned short (*Asw)[128 * 64] = (unsigned short(*)[128 * 64])shbuf;          // 2 x 16 KB
        unsigned short (*Bsw)[64 * 64] = (unsigned short(*)[64 * 64])(shbuf + 32768);  // 2 x 8 KB
        int row0 = (id / 12) * 128, col0 = (id % 12) * 64;
        bool is_doc = row0 < 2048;
        const float* A = is_doc ? (doc + row0 * 768) : (sume + (row0 - 2048) * 768);
        int kbase = is_doc ? 0 : 768;
        unsigned short* O = is_doc ? (hd + row0 * 768) : (hs + (row0 - 2048) * 768);

        int l = t & 63, w = t >> 6;
        int wr = w >> 1, wc = w & 1;
        int srow = t >> 3, sko = (t & 7) * 8;
        f32x4 acc[4][2];
        #pragma unroll
        for (int i = 0; i < 4; ++i)
            #pragma unroll
            for (int j = 0; j < 2; ++j) acc[i][j] = (f32x4)0.f;

        float4 fA0[4], fA1[4];
        bf16x8 bB[2];

#define G_LOAD(KT)                                                              \
        {                                                                       \
            _Pragma("unroll")                                                   \
            for (int p = 0; p < 4; ++p) {                                       \
                fA0[p] = *(const float4*)(A + (p * 32 + srow) * 768 + (KT) + sko); \
                fA1[p] = *(const float4*)(A + (p * 32 + srow) * 768 + (KT) + sko + 4); \
            }                                                                   \
            _Pragma("unroll")                                                   \
            for (int p = 0; p < 2; ++p)                                         \
                bB[p] = *(const bf16x8*)(W1t + (col0 + p * 32 + srow) * 1536 + kbase + (KT) + sko); \
        }

#define G_STORE(BUF)                                                            \
        {                                                                       \
            char* AB = (char*)Asw[BUF];                                         \
            char* BB = (char*)Bsw[BUF];                                         \
            _Pragma("unroll")                                                   \
            for (int p = 0; p < 4; ++p) {                                       \
                uint4 v = make_uint4(cvt_pk_bf16(fA0[p].x, fA0[p].y),           \
                                     cvt_pk_bf16(fA0[p].z, fA0[p].w),           \
                                     cvt_pk_bf16(fA1[p].x, fA1[p].y),           \
                                     cvt_pk_bf16(fA1[p].z, fA1[p].w));          \
                int r = p * 32 + srow;                                          \
                int byte = (r * 128 + sko * 2) ^ ((r & 7) << 4);                \
                *(uint4*)(AB + byte) = v;                                       \
            }                                                                   \
            _Pragma("unroll")                                                   \
            for (int p = 0; p < 2; ++p) {                                       \
                int r = p * 32 + srow;                                          \
                int byte = (r * 128 + sko * 2) ^ ((r & 7) << 4);                \
                *(bf16x8*)(BB + byte) = bB[p];                                  \
            }                                                                   \
        }

        G_LOAD(0)
        G_STORE(0)
        G_LOAD(64)
        soft_barrier();

        #pragma unroll 1
        for (int i = 0; i < 12; ++i) {
            int cur = i & 1;
            const char* AR = (const char*)Asw[cur];
            const char* BR = (const char*)Bsw[cur];
            #pragma unroll
            for (int ks = 0; ks < 2; ++ks) {
                int koff = (ks * 32 + (l >> 4) * 8) * 2;
                bf16x8 af[4], bfr[2];
                #pragma unroll
                for (int fr = 0; fr < 4; ++fr) {
                    int r = wr * 64 + fr * 16 + (l & 15);
                    af[fr] = *(const bf16x8*)(AR + ((r * 128 + koff) ^ ((r & 7) << 4)));
                }
                #pragma unroll
                for (int fc = 0; fc < 2; ++fc) {
                    int n = wc * 32 + fc * 16 + (l & 15);
                    bfr[fc] = *(const bf16x8*)(BR + ((n * 128 + koff) ^ ((n & 7) << 4)));
                }
                #pragma unroll
                for (int fr = 0; fr < 4; ++fr)
                    #pragma unroll
                    for (int fc = 0; fc < 2; ++fc)
                        acc[fr][fc] = __builtin_amdgcn_mfma_f32_16x16x32_bf16(af[fr], bfr[fc], acc[fr][fc], 0, 0, 0);
            }
            if (i < 11) {
                G_STORE(cur ^ 1)
                if (i < 10) G_LOAD((i + 2) * 64)
            }
            soft_barrier();
        }
#undef G_LOAD
#undef G_STORE

        #pragma unroll
        for (int fr = 0; fr < 4; ++fr)
            #pragma unroll
            for (int fc = 0; fc < 2; ++fc) {
                int c = col0 + wc * 32 + fc * 16 + (l & 15);
                float badd = is_doc ? 0.0f : b1[c];
                #pragma unroll
                for (int j = 0; j < 4; ++j) {
                    int r = wr * 64 + fr * 16 + (l >> 4) * 4 + j;
                    O[r * 768 + c] = f2bf(acc[fr][fc][j] + badd);
                }
            }
    } else if (id < 300) {
        // ---- W2 -> MFMA-fragment layout W2f ----
        unsigned short* sh = (unsigned short*)shbuf;   // [64][384]
        int kt = id - 288;
        #pragma unroll
        for (int p = 0; p < 96; ++p) {
            int u = p * 256 + t;
            int k = u / 384, n = u - k * 384;
            sh[u] = f2bf(W2[(kt * 64 + k) * 384 + n]);
        }
        __syncthreads();
        #pragma unroll
        for (int p = 0; p < 12; ++p) {
            int u = p * 256 + t;            // 0..3071
            int lane = u & 63;
            int g = u >> 6;                 // 0..47
            int ks = g / 24, fc = g - ks * 24;
            unsigned short tmp[8];
            #pragma unroll
            for (int j = 0; j < 8; ++j)
                tmp[j] = sh[(ks * 32 + (lane >> 4) * 8 + j) * 384 + fc * 16 + (lane & 15)];
            int ktks = kt * 2 + ks;
            *(uint4*)(W2f + ((ktks * 24 + fc) * 64 + lane) * 8) = *(uint4*)tmp;
        }
    } else {
        // ---- normalized bf16 rows for the cosine branch ----
        int row = (id - 300) * 4 + (t >> 6);
        int lane = t & 63;
        const float* p; unsigned short* dst;
        if (row < 2048) { p = doc + row * 768; dst = dnbf + row * 768; }
        else            { p = sume + (row - 2048) * 768; dst = snbf + (row - 2048) * 768; }
        const float* pp = p + lane * 12;
        float4 a0 = *(const float4*)(pp);
        float4 a1 = *(const float4*)(pp + 4);
        float4 a2 = *(const float4*)(pp + 8);
        float s = a0.x*a0.x + a0.y*a0.y + a0.z*a0.z + a0.w*a0.w
                + a1.x*a1.x + a1.y*a1.y + a1.z*a1.z + a1.w*a1.w
                + a2.x*a2.x + a2.y*a2.y + a2.z*a2.z + a2.w*a2.w;
        s = wave_sum(s);
        float r = rsqrtf(fmaxf(s, 1e-12f));
        unsigned short* dd = dst + lane * 12;
        dd[0]  = f2bf(a0.x * r); dd[1]  = f2bf(a0.y * r);
        dd[2]  = f2bf(a0.z * r); dd[3]  = f2bf(a0.w * r);
        dd[4]  = f2bf(a1.x * r); dd[5]  = f2bf(a1.y * r);
        dd[6]  = f2bf(a1.z * r); dd[7]  = f2bf(a1.w * r);
        dd[8]  = f2bf(a2.x * r); dd[9]  = f2bf(a2.y * r);
        dd[10] = f2bf(a2.z * r); dd[11] = f2bf(a2.w * r);
    }
}

// ---- main fused kernel (R14 configuration — measured best; UNCHANGED) ----
// blocks [0,32): MFMA cosine per b.
// blocks [32,544): score GEMM tile = 128 rows (2 s x 64 d) x 384 cols, 512 thr,
//   8 waves (2 row-grp x 4 col-grp => wave 64x96, acc 4x6 f32x4).
//   BK=32, 24 steps. DEEP PIPELINE: B triple-buffered (stage i+2 while reading i),
//   A regs double-set + LDS dbuf. Pre-barrier wait = vmcnt(5) — NEVER 0.
// LDS map: [0,8K) A0 | [8K,16K) A1 | [16K,+24K) B0 | B1 | B2  (88 KB total)
__global__ __launch_bounds__(512) void score_mfma(
    const unsigned short* __restrict__ hd, const unsigned short* __restrict__ hs,
    const unsigned short* __restrict__ W2f,
    const float* __restrict__ b2, const float* __restrict__ W3,
    const float* __restrict__ b3, const int* __restrict__ ndoc,
    const int* __restrict__ nseg, const unsigned short* __restrict__ dnbf,
    const unsigned short* __restrict__ snbf, float* __restrict__ out,
    float* __restrict__ dscos)
{
    __shared__ __align__(16) char smem[90112];
    float* spart = (float*)smem;          // [4][128] overlay (post-K-loop)
    float* sred  = (float*)smem;          // [4][32] (cosine branch)

    int t = threadIdx.x;
    int l = t & 63, w = t >> 6;

    if (blockIdx.x < 32) {
        // ---- cosine branch: one block per b ----
        int b = (int)blockIdx.x;
        if (w < 4) {
            const unsigned short* sb = snbf + b * 32 * 768;
            const unsigned short* db = dnbf + b * 64 * 768;
            int arow = l & 15, ak = (l >> 4) * 8;
            int d0 = w * 16;
            f32x4 acc0 = (f32x4)0.f, acc1 = (f32x4)0.f;
            #pragma unroll
            for (int k = 0; k < 768; k += 32) {
                bf16x8 a0 = *(const bf16x8*)(sb + arow * 768 + k + ak);
                bf16x8 a1 = *(const bf16x8*)(sb + (16 + arow) * 768 + k + ak);
                bf16x8 bb = *(const bf16x8*)(db + (d0 + arow) * 768 + k + ak);
                acc0 = __builtin_amdgcn_mfma_f32_16x16x32_bf16(a0, bb, acc0, 0, 0, 0);
                acc1 = __builtin_amdgcn_mfma_f32_16x16x32_bf16(a1, bb, acc1, 0, 0, 0);
            }
            int nd = ndoc[b];
            int d = d0 + (l & 15);
            float v0[4], v1[4];
            #pragma unroll
            for (int j = 0; j < 4; ++j) {
                v0[j] = (d < nd) ? (1.f - acc0[j]) * 0.5f : 0.f;
                v1[j] = (d < nd) ? (1.f - acc1[j]) * 0.5f : 0.f;
            }
            #pragma unroll
            for (int o = 1; o < 16; o <<= 1) {
                #pragma unroll
                for (int j = 0; j < 4; ++j) {
                    v0[j] = fmaxf(v0[j], __shfl_xor(v0[j], o));
                    v1[j] = fmaxf(v1[j], __shfl_xor(v1[j], o));
                }
            }
            if ((l & 15) == 0) {
                int srw = (l >> 4) * 4;
                #pragma unroll
                for (int j = 0; j < 4; ++j) {
                    sred[w * 32 + srw + j] = v0[j];
                    sred[w * 32 + 16 + srw + j] = v1[j];
                }
            }
        }
        __syncthreads();
        if (t < 32)
            dscos[(int)blockIdx.x * 32 + t] = fmaxf(fmaxf(sred[t], sred[32 + t]),
                                                    fmaxf(sred[64 + t], sred[96 + t]));
        return;
    }

    // ---- score branch ----
    int sb = (int)blockIdx.x - 32;                       // 0..511
    int lb = (sb & 7) * 64 + (sb >> 3);                  // XCD-contiguous
    int b = lb >> 4, sp = lb & 15;
    int s0 = sp * 2;
    int nd = ndoc[b], ns = nseg[b];
    int wr = w >> 2, wc = w & 3;            // 2 row-groups x 4 col-groups

    f32x4 acc[4][6];
    #pragma unroll
    for (int i = 0; i < 4; ++i)
        #pragma unroll
        for (int j = 0; j < 6; ++j) acc[i][j] = (f32x4)0.f;

    // A staging: thread t stages row r = t>>2 (0..127), k-octet k8 = t&3 (8 bf16)
    int r = t >> 2;
    int k8 = t & 3;
    int d = r & 63, sl = r >> 6;
    const unsigned short* hdp = hd + (b * 64 + d) * 768 + k8 * 8;
    const unsigned short* hsp = hs + (b * 32 + s0 + sl) * 768 + k8 * 8;
    int abyte = ((r >> 4) * 1024 + k8 * 256 + (r & 15) * 16) ^ (k8 << 4);  // bank-spread writes

    bf16x8 hdA, hsA, hdB, hsB;

#define A_LOAD(KT, HD8, HS8)                                                    \
    {                                                                           \
        HD8 = *(const bf16x8*)(hdp + (KT));                                     \
        HS8 = *(const bf16x8*)(hsp + (KT));                                     \
    }

#define B_STAGE(KC, BUF)                                                        \
    {                                                                           \
        _Pragma("unroll")                                                       \
        for (int q = 0; q < 3; ++q) {                                           \
            int fc = w * 3 + q;                                                 \
            const unsigned short* gsrc = W2f + (((KC) * 24 + fc) * 64 + l) * 8; \
            GLOAD_LDS16(gsrc, smem + 16384 + (BUF) * 24576 + fc * 1024);        \
        }                                                                       \
    }

#define A_STORE(HD8, HS8, BUF)                                                  \
    {                                                                           \
        const unsigned int* hu = (const unsigned int*)&HD8;                     \
        const unsigned int* su = (const unsigned int*)&HS8;                     \
        unsigned int au[4];                                                     \
        _Pragma("unroll")                                                       \
        for (int e = 0; e < 4; ++e) {                                           \
            float x0 = __uint_as_float(hu[e] << 16) + __uint_as_float(su[e] << 16); \
            float x1 = __uint_as_float(hu[e] & 0xffff0000u) + __uint_as_float(su[e] & 0xffff0000u); \
            au[e] = cvt_pk_bf16(gelu_fast(x0), gelu_fast(x1));                  \
        }                                                                       \
        *(uint4*)(smem + (BUF) * 8192 + abyte) = make_uint4(au[0], au[1], au[2], au[3]); \
    }

#define MFMA_PHASE(ABUF, BBUF)                                                  \
    {                                                                           \
        const char* AR = (const char*)smem + (ABUF) * 8192;                     \
        const char* BR = (const char*)smem + 16384 + (BBUF) * 24576;            \
        __builtin_amdgcn_s_setprio(1);                                          \
        bf16x8 af[4];                                                           \
        _Pragma("unroll")                                                       \
        for (int fr = 0; fr < 4; ++fr)                                          \
            af[fr] = *(const bf16x8*)(AR + (wr * 4 + fr) * 1024                 \
                                         + ((l * 16) ^ ((l >> 4) << 4)));       \
        _Pragma("unroll")                                                       \
        for (int i2 = 0; i2 < 6; ++i2) {                                        \
            bf16x8 bq = *(const bf16x8*)(BR + (wc * 6 + i2) * 1024 + l * 16);   \
            _Pragma("unroll")                                                   \
            for (int fr = 0; fr < 4; ++fr)                                      \
                acc[fr][i2] = __builtin_amdgcn_mfma_f32_16x16x32_bf16(af[fr], bq, acc[fr][i2], 0, 0, 0); \
        }                                                                       \
        __builtin_amdgcn_s_setprio(0);                                          \
    }

#define SYNC_CNT()                                                              \
    __builtin_amdgcn_sched_barrier(0);                                          \
    asm volatile("s_waitcnt vmcnt(5) lgkmcnt(0)" ::: "memory");                 \
    __builtin_amdgcn_s_barrier();                                               \
    __builtin_amdgcn_sched_barrier(0);

// one K-step; J = literal 0..5 (base multiple of 6 -> (base+J)%3 = J%3, parity = J&1)
#define K_ITER(J, HDL, HSL, HDS, HSS)                                           \
    {                                                                           \
        int i_ = base + (J);                                                    \
        if (i_ < 22) {                                                          \
            B_STAGE(i_ + 2, ((J) + 2) % 3)                                      \
            A_LOAD((i_ + 2) * 32, HDL, HSL)                                     \
        }                                                                       \
        MFMA_PHASE((J) & 1, (J) % 3)                                            \
        if (i_ < 23) A_STORE(HDS, HSS, ((J) + 1) & 1)                           \
        SYNC_CNT()                                                              \
    }

    // prologue: A(0)->set A; B(0)->buf0; B(1)->buf1; store A(0); A(1)->set B
    A_LOAD(0, hdA, hsA)
    B_STAGE(0, 0)
    B_STAGE(1, 1)
    A_STORE(hdA, hsA, 0)            // implicit wait on A(0); B0/B1 stay in flight
    A_LOAD(32, hdB, hsB)
    SYNC_CNT()                      // vmcnt(5): drains B0 only

    #pragma unroll 1
    for (int base = 0; base < 24; base += 6) {
        K_ITER(0, hdA, hsA, hdB, hsB)
        K_ITER(1, hdB, hsB, hdA, hsA)
        K_ITER(2, hdA, hsA, hdB, hsB)
        K_ITER(3, hdB, hsB, hdA, hsA)
        K_ITER(4, hdA, hsA, hdB, hsB)
        K_ITER(5, hdB, hsB, hdA, hsA)
    }
#undef A_LOAD
#undef B_STAGE
#undef A_STORE
#undef MFMA_PHASE
#undef SYNC_CNT
#undef K_ITER

    // epilogue: h2 = gelu(acc + b2); partial score over this wave's 96 cols
    float b2v[6], w3v[6];
    #pragma unroll
    for (int i2 = 0; i2 < 6; ++i2) {
        int col = wc * 96 + i2 * 16 + (l & 15);
        b2v[i2] = b2[col];
        w3v[i2] = W3[col];
    }
    __syncthreads();    // K-loop LDS reads done before spart overlays A-buffers
    #pragma unroll
    for (int fr = 0; fr < 4; ++fr) {
        #pragma unroll
        for (int j = 0; j < 4; ++j) {
            float pr = 0.f;
            #pragma unroll
            for (int i2 = 0; i2 < 6; ++i2)
                pr += gelu_fast(acc[fr][i2][j] + b2v[i2]) * w3v[i2];
            pr += __shfl_xor(pr, 1);
            pr += __shfl_xor(pr, 2);
            pr += __shfl_xor(pr, 4);
            pr += __shfl_xor(pr, 8);
            if ((l & 15) == 0)
                spart[wc * 128 + wr * 64 + fr * 16 + (l >> 4) * 4 + j] = pr;
        }
    }
    __syncthreads();
    if (t < 128) {
        int row = t;
        float v = spart[row] + spart[128 + row] + spart[256 + row] + spart[384 + row] + b3[0];
        float sc = sigmoid_fast(v);
        int dd = row & 63, sl2 = row >> 6;
        float m = (dd < nd) ? sc : 0.f;
        m = wave_max(m);
        if ((t & 63) == 0) {
            float segw = (ns > 10) ? 1.f : 100.f;
            out[1056 + b * 32 + s0 + sl2] = segw * m;
        }
    }
}

// ---- finish: passthrough outputs + cos_prior reduction ----
__global__ __launch_bounds__(1024) void finish_k(const float* __restrict__ agg,
                                                 const float* __restrict__ tinst,
                                                 const int* __restrict__ nseg,
                                                 const float* __restrict__ dscos,
                                                 float* __restrict__ out) {
    __shared__ float red[16];
    int t = threadIdx.x, lane = t & 63, w = t >> 6;
    int b = t >> 5, s = t & 31;
    int ns = nseg[b];
    out[32 + t] = (s < ns) ? tinst[t] : 1.0f;
    if (t < 32) {
        out[t] = agg[t];
        out[2080 + t] = (float)nseg[t];
    }
    float pred = out[1056 + t];
    float v = (s < ns) ? fabsf(dscos[t] - pred) / (float)ns : 0.f;
    v = wave_sum(v);
    if (lane == 0) red[w] = v;
    __syncthreads();
    if (w == 0) {
        float x = (lane < 16) ? red[lane] : 0.f;
        x = wave_sum(x);
        if (lane == 0) out[2112] = x * (1.f / 32.f);
    }
}

extern "C" void kernel_launch(void* const* d_in, const int* in_sizes, int n_in,
                              void* d_out, int out_size, void* d_ws, size_t ws_size,
                              hipStream_t stream) {
    const float* doc   = (const float*)d_in[0];   // [32,64,768]
    const float* sume  = (const float*)d_in[1];   // [32,32,768]
    const int*   ndoc  = (const int*)d_in[2];     // [32]
    const int*   nseg  = (const int*)d_in[3];     // [32]
    const float* agg   = (const float*)d_in[4];   // [32]
    const float* tinst = (const float*)d_in[5];   // [32,32]
    const float* W1    = (const float*)d_in[6];   // [1536,768]
    const float* b1    = (const float*)d_in[7];   // [768]
    const float* W2    = (const float*)d_in[8];   // [768,384]
    const float* b2    = (const float*)d_in[9];   // [384]
    const float* W3    = (const float*)d_in[10];  // [384,1]
    const float* b3    = (const float*)d_in[11];  // [1]
    float* out = (float*)d_out;
    char* ws = (char*)d_ws;

    unsigned short* hd   = (unsigned short*)(ws);             // [2048][768] bf16
    unsigned short* hs   = (unsigned short*)(ws + 3145728);   // [1024][768] bf16 (+b1)
    unsigned short* W1t  = (unsigned short*)(ws + 4718592);   // [768][1536] bf16
    unsigned short* W2f  = (unsigned short*)(ws + 7077888);   // frag-packed W2 bf16
    unsigned short* dnbf = (unsigned short*)(ws + 7667712);   // [2048][768] bf16 normalized
    unsigned short* snbf = (unsigned short*)(ws + 10813440);  // [1024][768] bf16 normalized
    float* dscos = (float*)(ws + 12386304);                   // 1024 f32

    prep_w1t<<<288, 256, 0, stream>>>(W1, W1t);
    mid_all<<<1068, 256, 0, stream>>>(doc, sume, W1t, b1, W2, hd, hs, W2f, dnbf, snbf);
    score_mfma<<<544, 512, 0, stream>>>(hd, hs, W2f, b2, W3, b3, ndoc, nseg,
                                        dnbf, snbf, out, dscos);
    finish_k<<<1, 1024, 0, stream>>>(agg, tinst, nseg, dscos, out);
}